// Round 4
// baseline (245.369 us; speedup 1.0000x reference)
//
#include <hip/hip_runtime.h>
#include <math.h>

// SANet attention, MFMA flash, two-phase fixed-max softmax + split-K.
// b=4, c=64, HW=4096, fp32 in/out.
// out[b,0:64,:] = content ; out[b,64:128,q] = sum_k Fst[:,k] softmax_k(Fc[:,q].Fs[:,k])
//
// prep_k: content copy + Vt[b][c][k]=(f16)Fst + Kt[b][k][c]=(f16)Fs (transposed).
// attn_k: 1 wave per (split, 16 q-rows). Phase 1: S-MFMA sweep of the split's
//   K-range tracking a per-lane max (no shfl/exp in loop); one cross-quad
//   reduction -> fixed M. Phase 2: recompute S (bitwise identical), P =
//   exp2(S' - M) (Q pre-scaled by log2e), per-lane row-sum, P->LDS->PV-MFMA.
//   No online rescale: acc is never multiplied by alpha.
// combine_k: merges 4 splits (exp2 domain).
//
// mfma_f32_16x16x32_f16: A[m=lane&15][k=quad*8+j], B[k=quad*8+j][n=lane&15],
// D[m=quad*4+reg][n=lane&15]  (quad = lane>>4).
// S-mfma computes S^T tile (m=k_key, n=q); PV computes O^T (m=c, n=q).
//
// __launch_bounds__(64,2): VGPR cap 256. R3's (64,4) squeezed VGPR to 44,
// serializing L2 load latency into the chain (~4700 cyc/tile). Need ~190 live.

#define Bb 4
#define Cc 64
#define HWs 4096
#define SPLITS 4
#define TILES_PER_SPLIT 16   // 64 K-tiles / 4 splits
#define RLOG2E 1.44269504088896340736f

typedef _Float16 half8 __attribute__((ext_vector_type(8)));
typedef _Float16 half4 __attribute__((ext_vector_type(4)));
typedef float floatx4 __attribute__((ext_vector_type(4)));

__global__ __launch_bounds__(256) void prep_k(const float* __restrict__ content,
                                              const float* __restrict__ Fs,
                                              const float* __restrict__ Fst,
                                              float* __restrict__ out,
                                              _Float16* __restrict__ Kt,
                                              _Float16* __restrict__ Vt) {
    const int bid = blockIdx.x;
    const int t = threadIdx.x;
    if (bid < 1024) {
        // content copy (float4) + V f16 convert (same linear layout)
        int i4 = bid * 256 + t;                       // 0..262143
        const float4* c4 = (const float4*)content;
        const float4* v4 = (const float4*)Fst;
        float4* o4 = (float4*)out;
        int b = i4 >> 16, rem = i4 & 65535;
        o4[(size_t)b * 131072 + rem] = c4[i4];        // out batch stride 2*64*4096 f32
        float4 v = v4[i4];
        half4 h;
        h[0] = (_Float16)v.x; h[1] = (_Float16)v.y;
        h[2] = (_Float16)v.z; h[3] = (_Float16)v.w;
        *(half4*)(Vt + (size_t)i4 * 4) = h;
    } else {
        // transpose+convert one 64c x 32hw tile of Fs -> Kt
        __shared__ _Float16 T[32][72];                // hw x c, padded
        int e = bid - 1024;                           // 0..511
        int b = e >> 7;
        int hw0 = (e & 127) * 32;
        const float* sb = Fs + (size_t)b * Cc * HWs;
        #pragma unroll
        for (int r = 0; r < 2; ++r) {
            int idx = r * 256 + t;                    // 0..511
            int c = idx >> 3, x4 = (idx & 7) * 4;     // c 0..63, x4 0..28
            float4 v = *(const float4*)(sb + (size_t)c * HWs + hw0 + x4);
            T[x4 + 0][c] = (_Float16)v.x;
            T[x4 + 1][c] = (_Float16)v.y;
            T[x4 + 2][c] = (_Float16)v.z;
            T[x4 + 3][c] = (_Float16)v.w;
        }
        __syncthreads();
        _Float16* db = Kt + (size_t)b * HWs * Cc;
        int row = t >> 3, g = t & 7;                  // row 0..31, g 0..7
        *(half8*)(db + (size_t)(hw0 + row) * Cc + g * 8) = *(half8*)&T[row][g * 8];
    }
}

__device__ __forceinline__ void load_kfr(const _Float16* __restrict__ Kb,
                                         int k0, int l15, int quad, half8 kf[4][2]) {
    #pragma unroll
    for (int m = 0; m < 4; ++m)
        #pragma unroll
        for (int cs = 0; cs < 2; ++cs)
            kf[m][cs] = *(const half8*)(Kb + (size_t)(k0 + m * 16 + l15) * Cc + cs * 32 + quad * 8);
}

__global__ __launch_bounds__(64, 2) void attn_k(const float* __restrict__ Fc,
                                                const _Float16* __restrict__ Kt,
                                                const _Float16* __restrict__ Vt,
                                                float* __restrict__ Opart,
                                                float2* __restrict__ ml) {
    const int lane = threadIdx.x;
    const int quad = lane >> 4;
    const int l15  = lane & 15;
    // block id: [split][b][qtile]  (qtile fastest)
    const int qt_i = blockIdx.x & 255;
    const int b    = (blockIdx.x >> 8) & 3;
    const int s    = blockIdx.x >> 10;
    const int q0   = qt_i * 16;
    const int k0base = s * TILES_PER_SPLIT * 64;

    __shared__ _Float16 Ps[16][80];   // P^T round-trip buffer, q x k, padded

    const float*    Fcb = Fc + (size_t)b * Cc * HWs;
    const _Float16* Kb  = Kt + (size_t)b * HWs * Cc;
    const _Float16* Vb  = Vt + (size_t)b * Cc * HWs;

    // Q B-frags from fp32 Fc, pre-scaled by log2(e) (one-time strided loads):
    // B[k=c][n=q]: qf0[j] = log2e * Fc[c=quad*8+j][q0+l15], qf1 -> c+32
    half8 qf0, qf1;
    #pragma unroll
    for (int j = 0; j < 8; ++j) {
        qf0[j] = (_Float16)(Fcb[(size_t)(quad * 8 + j) * HWs + q0 + l15] * RLOG2E);
        qf1[j] = (_Float16)(Fcb[(size_t)(32 + quad * 8 + j) * HWs + q0 + l15] * RLOG2E);
    }

    half8 ka[4][2], kan[4][2];

    // ---------- phase 1: fixed max over this split's K-range ----------
    float mloc = -INFINITY;
    load_kfr(Kb, k0base, l15, quad, ka);
    for (int kt = 0; kt < TILES_PER_SPLIT; ++kt) {
        load_kfr(Kb, k0base + ((kt + 1) & (TILES_PER_SPLIT - 1)) * 64, l15, quad, kan);
        floatx4 sv[4];
        #pragma unroll
        for (int m = 0; m < 4; ++m) {
            sv[m] = __builtin_amdgcn_mfma_f32_16x16x32_f16(ka[m][0], qf0, (floatx4)(0.0f), 0, 0, 0);
            sv[m] = __builtin_amdgcn_mfma_f32_16x16x32_f16(ka[m][1], qf1, sv[m], 0, 0, 0);
        }
        #pragma unroll
        for (int m = 0; m < 4; ++m)
            #pragma unroll
            for (int r = 0; r < 4; ++r) mloc = fmaxf(mloc, sv[m][r]);
        #pragma unroll
        for (int m = 0; m < 4; ++m)
            #pragma unroll
            for (int cs = 0; cs < 2; ++cs) ka[m][cs] = kan[m][cs];
    }
    mloc = fmaxf(mloc, __shfl_xor(mloc, 16));
    mloc = fmaxf(mloc, __shfl_xor(mloc, 32));
    const float M = mloc;   // per-q fixed max (log2 domain), uniform across quads

    // ---------- phase 2: P = exp2(S' - M), accumulate O and per-lane l ----------
    floatx4 acc[4];
    #pragma unroll
    for (int m = 0; m < 4; ++m) acc[m] = (floatx4)(0.0f);
    float lsum = 0.0f;

    load_kfr(Kb, k0base, l15, quad, ka);
    for (int kt = 0; kt < TILES_PER_SPLIT; ++kt) {
        const int k0 = k0base + kt * 64;
        // V A-frags: A[c=m*16+l15][k=ks*32+quad*8+j]
        half8 va[4][2];
        #pragma unroll
        for (int m = 0; m < 4; ++m)
            #pragma unroll
            for (int ks = 0; ks < 2; ++ks)
                va[m][ks] = *(const half8*)(Vb + (size_t)(m * 16 + l15) * HWs + k0 + ks * 32 + quad * 8);
        load_kfr(Kb, k0base + ((kt + 1) & (TILES_PER_SPLIT - 1)) * 64, l15, quad, kan);

        floatx4 sv[4];
        #pragma unroll
        for (int m = 0; m < 4; ++m) {
            sv[m] = __builtin_amdgcn_mfma_f32_16x16x32_f16(ka[m][0], qf0, (floatx4)(0.0f), 0, 0, 0);
            sv[m] = __builtin_amdgcn_mfma_f32_16x16x32_f16(ka[m][1], qf1, sv[m], 0, 0, 0);
        }
        #pragma unroll
        for (int m = 0; m < 4; ++m)
            #pragma unroll
            for (int r = 0; r < 4; ++r) {
                float e = exp2f(sv[m][r] - M);   // <= 1, no rescale ever needed
                sv[m][r] = e;
                lsum += e;
            }
        // P^T C-layout -> LDS Ps[q][k] (wave-private, no barrier)
        #pragma unroll
        for (int m = 0; m < 4; ++m) {
            half4 p;
            p[0] = (_Float16)sv[m][0]; p[1] = (_Float16)sv[m][1];
            p[2] = (_Float16)sv[m][2]; p[3] = (_Float16)sv[m][3];
            *(half4*)&Ps[l15][m * 16 + quad * 4] = p;
        }
        half8 pb0 = *(half8*)&Ps[l15][quad * 8];
        half8 pb1 = *(half8*)&Ps[l15][32 + quad * 8];

        // O^T update: D[m=c][n=q]
        #pragma unroll
        for (int m = 0; m < 4; ++m) {
            acc[m] = __builtin_amdgcn_mfma_f32_16x16x32_f16(va[m][0], pb0, acc[m], 0, 0, 0);
            acc[m] = __builtin_amdgcn_mfma_f32_16x16x32_f16(va[m][1], pb1, acc[m], 0, 0, 0);
        }
        #pragma unroll
        for (int m = 0; m < 4; ++m)
            #pragma unroll
            for (int cs = 0; cs < 2; ++cs) ka[m][cs] = kan[m][cs];
    }

    // row-sum: reduce per-lane partials across quads (once, not per tile)
    lsum += __shfl_xor(lsum, 16);
    lsum += __shfl_xor(lsum, 32);

    // write unnormalized partial O^T and (M, l)
    float* op = Opart + (((size_t)s * Bb + b) * Cc) * HWs;
    #pragma unroll
    for (int m = 0; m < 4; ++m)
        #pragma unroll
        for (int r = 0; r < 4; ++r) {
            int c = m * 16 + quad * 4 + r;
            op[(size_t)c * HWs + q0 + l15] = acc[m][r];
        }
    if (quad == 0)
        ml[((size_t)b * HWs + q0 + l15) * SPLITS + s] = make_float2(M, lsum);
}

__global__ __launch_bounds__(256) void combine_k(const float* __restrict__ Opart,
                                                 const float2* __restrict__ ml,
                                                 float* __restrict__ out) {
    int idx = blockIdx.x * 256 + threadIdx.x;         // over 4*64*4096 = 1M
    int q = idx & 4095;
    int c = (idx >> 12) & 63;
    int b = idx >> 18;
    const float2* mlp = ml + ((size_t)b * HWs + q) * SPLITS;
    float2 mls[SPLITS];
    #pragma unroll
    for (int s = 0; s < SPLITS; ++s) mls[s] = mlp[s];
    float M = -INFINITY;
    #pragma unroll
    for (int s = 0; s < SPLITS; ++s) M = fmaxf(M, mls[s].x);
    float l = 0.0f, w[SPLITS];
    #pragma unroll
    for (int s = 0; s < SPLITS; ++s) {
        w[s] = exp2f(mls[s].x - M);                   // log2 domain
        l += w[s] * mls[s].y;
    }
    float o = 0.0f;
    #pragma unroll
    for (int s = 0; s < SPLITS; ++s)
        o += w[s] * Opart[(((size_t)s * Bb + b) * Cc + c) * HWs + q];
    out[((size_t)b * 2 * Cc + Cc + c) * HWs + q] = o / l;
}

extern "C" void kernel_launch(void* const* d_in, const int* in_sizes, int n_in,
                              void* d_out, int out_size, void* d_ws, size_t ws_size,
                              hipStream_t stream) {
    const float* content   = (const float*)d_in[0];
    const float* content_s = (const float*)d_in[1];
    const float* style     = (const float*)d_in[2];
    float* out = (float*)d_out;

    _Float16* Kt = (_Float16*)d_ws;                           // [4][4096][64] f16  (2 MB)
    _Float16* Vt = Kt + (size_t)Bb * HWs * Cc;                // [4][64][4096] f16  (2 MB)
    float*    Opart = (float*)(Vt + (size_t)Bb * Cc * HWs);   // [4][4][64][4096]  (16.8 MB)
    float2*   ml = (float2*)(Opart + (size_t)SPLITS * Bb * Cc * HWs);  // [4][4096][4] (512 KB)

    prep_k<<<dim3(1536), dim3(256), 0, stream>>>(content, content_s, style, out, Kt, Vt);
    attn_k<<<dim3(SPLITS * Bb * (HWs / 16)), dim3(64), 0, stream>>>(content, Kt, Vt, Opart, ml);
    combine_k<<<dim3(4096), dim3(256), 0, stream>>>(Opart, ml, out);
}

// Round 5
// 111.093 us; speedup vs baseline: 2.2087x; 2.2087x over previous
//
#include <hip/hip_runtime.h>
#include <math.h>

// SANet attention: MFMA flash, LDS-staged K/V tiles (xor-swizzled), split-K.
// b=4, c=64, HW=4096, fp32 in/out.
// out[b,0:64,:] = content ; out[b,64:128,q] = sum_k Fst[:,k] softmax_k(Fc[:,q].Fs[:,k])
//
// R2-R4 evidence: per-wave strided fragment loads (lane stride 128B -> 16
// cache lines/instr) saturate the per-CU vmem pipe; throughput was invariant
// to TLP. R5: 512-thread WG (8 waves, 128 q-rows) stages K/V tiles into LDS
// once (coalesced 16B/lane), double-buffered, 1 barrier/iter; frags via
// ds_read_b128 from xor-swizzled layout (conflict-free); online softmax.
//
// mfma_f32_16x16x32_f16: A[m=lane&15][k=quad*8+j], B[k=quad*8+j][n=lane&15],
// D[m=quad*4+reg][n=lane&15]  (quad = lane>>4).
// S-mfma computes S^T tile (m=k_key, n=q); PV computes O^T (m=c, n=q).

#define Bb 4
#define Cc 64
#define HWs 4096
#define SPLITS 4
#define TILES_PER_SPLIT 16      // 1024 k per split / 64
#define RLOG2E 1.44269504088896340736f

typedef _Float16 half8 __attribute__((ext_vector_type(8)));
typedef _Float16 half4 __attribute__((ext_vector_type(4)));
typedef float floatx4 __attribute__((ext_vector_type(4)));

// ---------------- prep: content copy + Vt convert + Kt transpose ----------------
__global__ __launch_bounds__(256) void prep_k(const float* __restrict__ content,
                                              const float* __restrict__ Fs,
                                              const float* __restrict__ Fst,
                                              float* __restrict__ out,
                                              _Float16* __restrict__ Kt,
                                              _Float16* __restrict__ Vt) {
    const int bid = blockIdx.x;
    const int t = threadIdx.x;
    if (bid < 1024) {
        // content copy (float4) + V f16 convert (same linear layout)
        int i4 = bid * 256 + t;                       // 0..262143
        const float4* c4 = (const float4*)content;
        const float4* v4 = (const float4*)Fst;
        float4* o4 = (float4*)out;
        int b = i4 >> 16, rem = i4 & 65535;
        o4[(size_t)b * 131072 + rem] = c4[i4];        // out batch stride 2*64*4096 f32
        float4 v = v4[i4];
        half4 h;
        h[0] = (_Float16)v.x; h[1] = (_Float16)v.y;
        h[2] = (_Float16)v.z; h[3] = (_Float16)v.w;
        *(half4*)(Vt + (size_t)i4 * 4) = h;
    } else {
        // transpose+convert one 16hw x 64c tile of Fs -> Kt[b][k][c]
        __shared__ _Float16 T[16][72];
        int e = bid - 1024;                           // 0..1023
        int b = e >> 8;
        int hw0 = (e & 255) * 16;
        const float* sb = Fs + (size_t)b * Cc * HWs;
        {
            int c = t >> 2, x4 = (t & 3) * 4;         // 256 float4 = whole tile
            float4 v = *(const float4*)(sb + (size_t)c * HWs + hw0 + x4);
            T[x4 + 0][c] = (_Float16)v.x;
            T[x4 + 1][c] = (_Float16)v.y;
            T[x4 + 2][c] = (_Float16)v.z;
            T[x4 + 3][c] = (_Float16)v.w;
        }
        __syncthreads();
        if (t < 128) {
            int row = t >> 3, g = t & 7;
            _Float16* db = Kt + (size_t)b * HWs * Cc;
            *(half8*)(db + (size_t)(hw0 + row) * Cc + g * 8) = *(half8*)&T[row][g * 8];
        }
    }
}

// ---------------- attn: flash with LDS-staged tiles ----------------
__global__ __launch_bounds__(512, 4) void attn_k(const float* __restrict__ Fc,
                                                 const _Float16* __restrict__ Kt,
                                                 const _Float16* __restrict__ Vt,
                                                 float* __restrict__ Opart,
                                                 float2* __restrict__ ml) {
    const int tid  = threadIdx.x;                 // 0..511
    const int w    = tid >> 6;                    // wave 0..7
    const int lane = tid & 63;
    const int quad = lane >> 4;
    const int l15  = lane & 15;
    // block: [split][b][qgroup]
    const int qg = blockIdx.x & 31;
    const int b  = (blockIdx.x >> 5) & 3;
    const int s  = blockIdx.x >> 7;
    const int k0base = s * TILES_PER_SPLIT * 64;
    const int q = qg * 128 + w * 16 + l15;        // this lane's q-row

    // xor-swizzled tiles: chunk j of row r stored at chunk j^(r&7)
    __shared__ _Float16 Kl[2][64 * 64];
    __shared__ _Float16 Vl[2][64 * 64];
    __shared__ _Float16 Ps[8][16][80];            // per-wave P^T roundtrip, padded

    const float*    Fcb = Fc + (size_t)b * Cc * HWs;
    const _Float16* Kb  = Kt + (size_t)b * HWs * Cc;
    const _Float16* Vb  = Vt + (size_t)b * Cc * HWs;

    // staging role: tids 0..255 stage K, 256..511 stage V; 2 chunks each
    const bool isK  = tid < 256;
    const int  sl   = tid & 255;
    const int  srow = sl >> 3;                    // 0..31 (and +32)
    const int  sjg  = sl & 7;                     // global 16B chunk in row
    const int  ssw  = (sjg ^ (srow & 7)) * 8;     // swizzled LDS chunk (same for row+32)

    // Q B-frags from fp32 Fc, pre-scaled by log2e (one-time strided loads)
    half8 qf0, qf1;
    #pragma unroll
    for (int j = 0; j < 8; ++j) {
        qf0[j] = (_Float16)(Fcb[(size_t)(quad * 8 + j) * HWs + q] * RLOG2E);
        qf1[j] = (_Float16)(Fcb[(size_t)(32 + quad * 8 + j) * HWs + q] * RLOG2E);
    }

    half8 st0, st1;
    // stage load for tile kt -> regs
    auto stage_load = [&](int kt) {
        int kk0 = k0base + kt * 64;
        if (isK) {
            st0 = *(const half8*)(Kb + (size_t)(kk0 + srow) * 64 + sjg * 8);
            st1 = *(const half8*)(Kb + (size_t)(kk0 + 32 + srow) * 64 + sjg * 8);
        } else {
            st0 = *(const half8*)(Vb + (size_t)srow * HWs + kk0 + sjg * 8);
            st1 = *(const half8*)(Vb + (size_t)(32 + srow) * HWs + kk0 + sjg * 8);
        }
    };
    auto stage_write = [&](int p) {
        if (isK) {
            *(half8*)&Kl[p][srow * 64 + ssw]        = st0;
            *(half8*)&Kl[p][(32 + srow) * 64 + ssw] = st1;
        } else {
            *(half8*)&Vl[p][srow * 64 + ssw]        = st0;
            *(half8*)&Vl[p][(32 + srow) * 64 + ssw] = st1;
        }
    };

    floatx4 acc[4];
    #pragma unroll
    for (int m = 0; m < 4; ++m) acc[m] = (floatx4)(0.0f);
    float m_run = -INFINITY, lsum = 0.0f;

    // pipeline preamble
    stage_load(0);
    stage_write(0);
    stage_load(1);
    __syncthreads();

    const int swl = (l15 & 7);                    // row-swizzle term for frag reads
    for (int kt = 0; kt < TILES_PER_SPLIT; ++kt) {
        const int p = kt & 1;
        if (kt + 1 < TILES_PER_SPLIT) stage_write(p ^ 1);
        if (kt + 2 < TILES_PER_SPLIT) stage_load(kt + 2);

        // K A-frags from LDS: row k = m*16+l15, chunk j = cs*4+quad
        half8 ka[4][2];
        #pragma unroll
        for (int m = 0; m < 4; ++m)
            #pragma unroll
            for (int cs = 0; cs < 2; ++cs)
                ka[m][cs] = *(const half8*)&Kl[p][(m * 16 + l15) * 64 + (((cs * 4 + quad) ^ swl) * 8)];

        floatx4 sv[4];
        #pragma unroll
        for (int m = 0; m < 4; ++m) {
            sv[m] = __builtin_amdgcn_mfma_f32_16x16x32_f16(ka[m][0], qf0, (floatx4)(0.0f), 0, 0, 0);
            sv[m] = __builtin_amdgcn_mfma_f32_16x16x32_f16(ka[m][1], qf1, sv[m], 0, 0, 0);
        }

        // V A-frags (issue early, consumed after softmax)
        half8 va[4][2];
        #pragma unroll
        for (int m = 0; m < 4; ++m)
            #pragma unroll
            for (int ks = 0; ks < 2; ++ks)
                va[m][ks] = *(const half8*)&Vl[p][(m * 16 + l15) * 64 + (((ks * 4 + quad) ^ swl) * 8)];

        // online softmax (log2 domain)
        float mx = -INFINITY;
        #pragma unroll
        for (int m = 0; m < 4; ++m)
            #pragma unroll
            for (int r = 0; r < 4; ++r) mx = fmaxf(mx, sv[m][r]);
        mx = fmaxf(mx, __shfl_xor(mx, 16));
        mx = fmaxf(mx, __shfl_xor(mx, 32));
        float m_new = fmaxf(m_run, mx);
        float alpha = exp2f(m_run - m_new);       // 0 on first tile
        m_run = m_new;
        float part = 0.0f;
        #pragma unroll
        for (int m = 0; m < 4; ++m)
            #pragma unroll
            for (int r = 0; r < 4; ++r) {
                float e = exp2f(sv[m][r] - m_new);
                sv[m][r] = e;
                part += e;
            }
        lsum = lsum * alpha + part;               // per-lane; quad-reduced at end
        #pragma unroll
        for (int m = 0; m < 4; ++m)
            #pragma unroll
            for (int r = 0; r < 4; ++r) acc[m][r] *= alpha;

        // P^T C-layout -> LDS -> B-frag (wave-private, no barrier)
        #pragma unroll
        for (int m = 0; m < 4; ++m) {
            half4 pp;
            pp[0] = (_Float16)sv[m][0]; pp[1] = (_Float16)sv[m][1];
            pp[2] = (_Float16)sv[m][2]; pp[3] = (_Float16)sv[m][3];
            *(half4*)&Ps[w][l15][m * 16 + quad * 4] = pp;
        }
        half8 pb0 = *(half8*)&Ps[w][l15][quad * 8];
        half8 pb1 = *(half8*)&Ps[w][l15][32 + quad * 8];

        #pragma unroll
        for (int m = 0; m < 4; ++m) {
            acc[m] = __builtin_amdgcn_mfma_f32_16x16x32_f16(va[m][0], pb0, acc[m], 0, 0, 0);
            acc[m] = __builtin_amdgcn_mfma_f32_16x16x32_f16(va[m][1], pb1, acc[m], 0, 0, 0);
        }

        __syncthreads();                          // one barrier per tile
    }

    // reduce row-sum across quads (once)
    lsum += __shfl_xor(lsum, 16);
    lsum += __shfl_xor(lsum, 32);

    // write unnormalized partial O^T and (M, l)
    float* op = Opart + (((size_t)s * Bb + b) * Cc) * HWs;
    #pragma unroll
    for (int m = 0; m < 4; ++m)
        #pragma unroll
        for (int r = 0; r < 4; ++r) {
            int c = m * 16 + quad * 4 + r;
            op[(size_t)c * HWs + q] = acc[m][r];
        }
    if (quad == 0)
        ml[((size_t)b * HWs + q) * SPLITS + s] = make_float2(m_run, lsum);
}

// ---------------- combine: merge splits (exp2 domain) ----------------
__global__ __launch_bounds__(256) void combine_k(const float* __restrict__ Opart,
                                                 const float2* __restrict__ ml,
                                                 float* __restrict__ out) {
    int idx = blockIdx.x * 256 + threadIdx.x;     // over 4*64*4096 = 1M
    int q = idx & 4095;
    int c = (idx >> 12) & 63;
    int b = idx >> 18;
    const float2* mlp = ml + ((size_t)b * HWs + q) * SPLITS;
    float2 mls[SPLITS];
    #pragma unroll
    for (int s = 0; s < SPLITS; ++s) mls[s] = mlp[s];
    float M = -INFINITY;
    #pragma unroll
    for (int s = 0; s < SPLITS; ++s) M = fmaxf(M, mls[s].x);
    float l = 0.0f, wgt[SPLITS];
    #pragma unroll
    for (int s = 0; s < SPLITS; ++s) {
        wgt[s] = exp2f(mls[s].x - M);
        l += wgt[s] * mls[s].y;
    }
    float o = 0.0f;
    #pragma unroll
    for (int s = 0; s < SPLITS; ++s)
        o += wgt[s] * Opart[(((size_t)s * Bb + b) * Cc + c) * HWs + q];
    out[((size_t)b * 2 * Cc + Cc + c) * HWs + q] = o / l;
}

extern "C" void kernel_launch(void* const* d_in, const int* in_sizes, int n_in,
                              void* d_out, int out_size, void* d_ws, size_t ws_size,
                              hipStream_t stream) {
    const float* content   = (const float*)d_in[0];
    const float* content_s = (const float*)d_in[1];
    const float* style     = (const float*)d_in[2];
    float* out = (float*)d_out;

    _Float16* Kt = (_Float16*)d_ws;                           // [4][4096][64] f16  (2 MB)
    _Float16* Vt = Kt + (size_t)Bb * HWs * Cc;                // [4][64][4096] f16  (2 MB)
    float*    Opart = (float*)(Vt + (size_t)Bb * Cc * HWs);   // [SPLITS][4][64][4096] f32
    float2*   ml = (float2*)(Opart + (size_t)SPLITS * Bb * Cc * HWs);  // [4][4096][SPLITS]

    prep_k<<<dim3(2048), dim3(256), 0, stream>>>(content, content_s, style, out, Kt, Vt);
    attn_k<<<dim3(SPLITS * Bb * 32), dim3(512), 0, stream>>>(content, Kt, Vt, Opart, ml);
    combine_k<<<dim3(4096), dim3(256), 0, stream>>>(Opart, ml, out);
}

// Round 6
// 110.132 us; speedup vs baseline: 2.2280x; 1.0087x over previous
//
#include <hip/hip_runtime.h>
#include <math.h>

// SANet attention: MFMA flash, LDS-staged K/V (xor-swizzled), 32 q-rows/wave,
// split-K, f16 partials. b=4, c=64, HW=4096, fp32 in/out.
// out[b,0:64,:] = content ; out[b,64:128,q] = sum_k Fst[:,k] softmax_k(Fc[:,q].Fs[:,k])
//
// R5 post-mortem: LDS pipe bound (16 waves/CU x ~26 LDS ops/tile). R6: each
// wave covers 32 q-rows (2 Q B-frag pairs share every K/V fragment read) ->
// half the waves, half the per-CU LDS traffic for the same MACs. Ps stride
// 72 halfs (144 B) -> b64 writes 2-way (free); Opart in f16.
//
// mfma_f32_16x16x32_f16: A[m=lane&15][k=quad*8+j], B[k=quad*8+j][n=lane&15],
// D[m=quad*4+reg][n=lane&15]  (quad = lane>>4).
// S-mfma computes S^T tile (m=k_key, n=q); PV computes O^T (m=c, n=q).

#define Bb 4
#define Cc 64
#define HWs 4096
#define SPLITS 4
#define TILES_PER_SPLIT 16      // 1024 k per split / 64
#define RLOG2E 1.44269504088896340736f

typedef _Float16 half8 __attribute__((ext_vector_type(8)));
typedef _Float16 half4 __attribute__((ext_vector_type(4)));
typedef float floatx4 __attribute__((ext_vector_type(4)));

// ---------------- prep: content copy + Vt convert + Kt transpose ----------------
__global__ __launch_bounds__(256) void prep_k(const float* __restrict__ content,
                                              const float* __restrict__ Fs,
                                              const float* __restrict__ Fst,
                                              float* __restrict__ out,
                                              _Float16* __restrict__ Kt,
                                              _Float16* __restrict__ Vt) {
    const int bid = blockIdx.x;
    const int t = threadIdx.x;
    if (bid < 1024) {
        // content copy (float4) + V f16 convert (same linear layout)
        int i4 = bid * 256 + t;                       // 0..262143
        const float4* c4 = (const float4*)content;
        const float4* v4 = (const float4*)Fst;
        float4* o4 = (float4*)out;
        int b = i4 >> 16, rem = i4 & 65535;
        o4[(size_t)b * 131072 + rem] = c4[i4];        // out batch stride 2*64*4096 f32
        float4 v = v4[i4];
        half4 h;
        h[0] = (_Float16)v.x; h[1] = (_Float16)v.y;
        h[2] = (_Float16)v.z; h[3] = (_Float16)v.w;
        *(half4*)(Vt + (size_t)i4 * 4) = h;
    } else {
        // transpose+convert one 16hw x 64c tile of Fs -> Kt[b][k][c]
        __shared__ _Float16 T[16][72];
        int e = bid - 1024;                           // 0..1023
        int b = e >> 8;
        int hw0 = (e & 255) * 16;
        const float* sb = Fs + (size_t)b * Cc * HWs;
        {
            int c = t >> 2, x4 = (t & 3) * 4;         // 256 float4 = whole tile
            float4 v = *(const float4*)(sb + (size_t)c * HWs + hw0 + x4);
            T[x4 + 0][c] = (_Float16)v.x;
            T[x4 + 1][c] = (_Float16)v.y;
            T[x4 + 2][c] = (_Float16)v.z;
            T[x4 + 3][c] = (_Float16)v.w;
        }
        __syncthreads();
        if (t < 128) {
            int row = t >> 3, g = t & 7;
            _Float16* db = Kt + (size_t)b * HWs * Cc;
            *(half8*)(db + (size_t)(hw0 + row) * Cc + g * 8) = *(half8*)&T[row][g * 8];
        }
    }
}

// ---------------- attn: flash, LDS tiles, 32 q/wave ----------------
__global__ __launch_bounds__(256, 2) void attn_k(const float* __restrict__ Fc,
                                                 const _Float16* __restrict__ Kt,
                                                 const _Float16* __restrict__ Vt,
                                                 _Float16* __restrict__ Opart,
                                                 float2* __restrict__ ml) {
    const int tid  = threadIdx.x;                 // 0..255
    const int w    = tid >> 6;                    // wave 0..3
    const int lane = tid & 63;
    const int quad = lane >> 4;
    const int l15  = lane & 15;
    // block: [split][b][qgroup]
    const int qg = blockIdx.x & 31;
    const int b  = (blockIdx.x >> 5) & 3;
    const int s  = blockIdx.x >> 7;
    const int k0base = s * TILES_PER_SPLIT * 64;
    const int qA = qg * 128 + w * 32 + l15;       // group 0 q-row
    const int qB = qA + 16;                       // group 1 q-row

    // xor-swizzled tiles: 16B chunk j of row r stored at chunk j^(r&7)
    __shared__ _Float16 Kl[2][64 * 64];
    __shared__ _Float16 Vl[2][64 * 64];
    __shared__ _Float16 Ps[4][32][72];            // per-wave P^T roundtrip, stride 144B

    const float*    Fcb = Fc + (size_t)b * Cc * HWs;
    const _Float16* Kb  = Kt + (size_t)b * HWs * Cc;
    const _Float16* Vb  = Vt + (size_t)b * Cc * HWs;

    // staging role: tids 0..127 stage K, 128..255 stage V; 4 chunks each
    const bool isK  = tid < 128;
    const int  sl   = tid & 127;
    const int  srow = sl >> 3;                    // 0..15 (+16i)
    const int  sjg  = sl & 7;                     // global 16B chunk in row
    const int  ssw  = (sjg ^ (srow & 7)) * 8;     // swizzled chunk offset (halfs)

    // Q B-frags from fp32 Fc, pre-scaled by log2e (one-time strided loads)
    half8 qf[2][2];
    #pragma unroll
    for (int j = 0; j < 8; ++j) {
        qf[0][0][j] = (_Float16)(Fcb[(size_t)(quad * 8 + j) * HWs + qA] * RLOG2E);
        qf[0][1][j] = (_Float16)(Fcb[(size_t)(32 + quad * 8 + j) * HWs + qA] * RLOG2E);
        qf[1][0][j] = (_Float16)(Fcb[(size_t)(quad * 8 + j) * HWs + qB] * RLOG2E);
        qf[1][1][j] = (_Float16)(Fcb[(size_t)(32 + quad * 8 + j) * HWs + qB] * RLOG2E);
    }

    half8 st[4];
    auto stage_load = [&](int kt) {
        int kk0 = k0base + kt * 64;
        #pragma unroll
        for (int i = 0; i < 4; ++i) {
            int row = srow + 16 * i;
            if (isK) st[i] = *(const half8*)(Kb + (size_t)(kk0 + row) * 64 + sjg * 8);
            else     st[i] = *(const half8*)(Vb + (size_t)row * HWs + kk0 + sjg * 8);
        }
    };
    auto stage_write = [&](int p) {
        #pragma unroll
        for (int i = 0; i < 4; ++i) {
            int row = srow + 16 * i;
            if (isK) *(half8*)&Kl[p][row * 64 + ssw] = st[i];
            else     *(half8*)&Vl[p][row * 64 + ssw] = st[i];
        }
    };

    floatx4 acc[2][4];
    #pragma unroll
    for (int g = 0; g < 2; ++g)
        #pragma unroll
        for (int m = 0; m < 4; ++m) acc[g][m] = (floatx4)(0.0f);
    float m_run[2] = {-INFINITY, -INFINITY};
    float lsum[2] = {0.0f, 0.0f};

    stage_load(0);
    stage_write(0);
    stage_load(1);
    __syncthreads();

    const int swl = (l15 & 7);
    for (int kt = 0; kt < TILES_PER_SPLIT; ++kt) {
        const int p = kt & 1;
        if (kt + 1 < TILES_PER_SPLIT) stage_write(p ^ 1);
        if (kt + 2 < TILES_PER_SPLIT) stage_load(kt + 2);

        // K A-frags: row k = m*16+l15, chunk j = (cs*4+quad)^(row&7)
        half8 ka[4][2];
        #pragma unroll
        for (int m = 0; m < 4; ++m)
            #pragma unroll
            for (int cs = 0; cs < 2; ++cs)
                ka[m][cs] = *(const half8*)&Kl[p][(m * 16 + l15) * 64 + (((cs * 4 + quad) ^ swl) * 8)];

        floatx4 sv[2][4];
        #pragma unroll
        for (int m = 0; m < 4; ++m) {
            #pragma unroll
            for (int g = 0; g < 2; ++g) {
                sv[g][m] = __builtin_amdgcn_mfma_f32_16x16x32_f16(ka[m][0], qf[g][0], (floatx4)(0.0f), 0, 0, 0);
                sv[g][m] = __builtin_amdgcn_mfma_f32_16x16x32_f16(ka[m][1], qf[g][1], sv[g][m], 0, 0, 0);
            }
        }

        // V A-frags (issued early; consumed after softmax)
        half8 va[4][2];
        #pragma unroll
        for (int m = 0; m < 4; ++m)
            #pragma unroll
            for (int ks = 0; ks < 2; ++ks)
                va[m][ks] = *(const half8*)&Vl[p][(m * 16 + l15) * 64 + (((ks * 4 + quad) ^ swl) * 8)];

        // online softmax per q-group (log2 domain)
        half8 pb[2][2];
        #pragma unroll
        for (int g = 0; g < 2; ++g) {
            float mx = -INFINITY;
            #pragma unroll
            for (int m = 0; m < 4; ++m)
                #pragma unroll
                for (int r = 0; r < 4; ++r) mx = fmaxf(mx, sv[g][m][r]);
            mx = fmaxf(mx, __shfl_xor(mx, 16));
            mx = fmaxf(mx, __shfl_xor(mx, 32));
            float m_new = fmaxf(m_run[g], mx);
            float alpha = exp2f(m_run[g] - m_new);    // 0 on first tile
            m_run[g] = m_new;
            float part = 0.0f;
            #pragma unroll
            for (int m = 0; m < 4; ++m)
                #pragma unroll
                for (int r = 0; r < 4; ++r) {
                    float e = exp2f(sv[g][m][r] - m_new);
                    sv[g][m][r] = e;
                    part += e;
                }
            lsum[g] = lsum[g] * alpha + part;
            #pragma unroll
            for (int m = 0; m < 4; ++m)
                #pragma unroll
                for (int r = 0; r < 4; ++r) acc[g][m][r] *= alpha;

            // P^T C-layout -> LDS (wave-private, no barrier)
            #pragma unroll
            for (int m = 0; m < 4; ++m) {
                half4 pp;
                pp[0] = (_Float16)sv[g][m][0]; pp[1] = (_Float16)sv[g][m][1];
                pp[2] = (_Float16)sv[g][m][2]; pp[3] = (_Float16)sv[g][m][3];
                *(half4*)&Ps[w][g * 16 + l15][m * 16 + quad * 4] = pp;
            }
            pb[g][0] = *(half8*)&Ps[w][g * 16 + l15][quad * 8];
            pb[g][1] = *(half8*)&Ps[w][g * 16 + l15][32 + quad * 8];
        }

        // O^T update: D[m=c][n=q]
        #pragma unroll
        for (int m = 0; m < 4; ++m)
            #pragma unroll
            for (int g = 0; g < 2; ++g) {
                acc[g][m] = __builtin_amdgcn_mfma_f32_16x16x32_f16(va[m][0], pb[g][0], acc[g][m], 0, 0, 0);
                acc[g][m] = __builtin_amdgcn_mfma_f32_16x16x32_f16(va[m][1], pb[g][1], acc[g][m], 0, 0, 0);
            }

        __syncthreads();                          // one barrier per tile
    }

    // reduce row-sums across quads (once), write partials (f16) + (M,l)
    _Float16* op = Opart + (((size_t)s * Bb + b) * Cc) * HWs;
    #pragma unroll
    for (int g = 0; g < 2; ++g) {
        lsum[g] += __shfl_xor(lsum[g], 16);
        lsum[g] += __shfl_xor(lsum[g], 32);
        int q = (g == 0) ? qA : qB;
        #pragma unroll
        for (int m = 0; m < 4; ++m)
            #pragma unroll
            for (int r = 0; r < 4; ++r) {
                int c = m * 16 + quad * 4 + r;
                op[(size_t)c * HWs + q] = (_Float16)acc[g][m][r];
            }
        if (quad == 0)
            ml[((size_t)b * HWs + q) * SPLITS + s] = make_float2(m_run[g], lsum[g]);
    }
}

// ---------------- combine: merge splits (exp2 domain) ----------------
__global__ __launch_bounds__(256) void combine_k(const _Float16* __restrict__ Opart,
                                                 const float2* __restrict__ ml,
                                                 float* __restrict__ out) {
    int idx = blockIdx.x * 256 + threadIdx.x;     // over 4*64*4096 = 1M
    int q = idx & 4095;
    int c = (idx >> 12) & 63;
    int b = idx >> 18;
    const float2* mlp = ml + ((size_t)b * HWs + q) * SPLITS;
    float2 mls[SPLITS];
    #pragma unroll
    for (int s = 0; s < SPLITS; ++s) mls[s] = mlp[s];
    float M = -INFINITY;
    #pragma unroll
    for (int s = 0; s < SPLITS; ++s) M = fmaxf(M, mls[s].x);
    float l = 0.0f, wgt[SPLITS];
    #pragma unroll
    for (int s = 0; s < SPLITS; ++s) {
        wgt[s] = exp2f(mls[s].x - M);
        l += wgt[s] * mls[s].y;
    }
    float o = 0.0f;
    #pragma unroll
    for (int s = 0; s < SPLITS; ++s)
        o += wgt[s] * (float)Opart[(((size_t)s * Bb + b) * Cc + c) * HWs + q];
    out[((size_t)b * 2 * Cc + Cc + c) * HWs + q] = o / l;
}

extern "C" void kernel_launch(void* const* d_in, const int* in_sizes, int n_in,
                              void* d_out, int out_size, void* d_ws, size_t ws_size,
                              hipStream_t stream) {
    const float* content   = (const float*)d_in[0];
    const float* content_s = (const float*)d_in[1];
    const float* style     = (const float*)d_in[2];
    float* out = (float*)d_out;

    _Float16* Kt = (_Float16*)d_ws;                           // [4][4096][64] f16  (2 MB)
    _Float16* Vt = Kt + (size_t)Bb * HWs * Cc;                // [4][64][4096] f16  (2 MB)
    _Float16* Opart = Vt + (size_t)Bb * Cc * HWs;             // [SPLITS][4][64][4096] f16 (8.4 MB)
    float2*   ml = (float2*)(Opart + (size_t)SPLITS * Bb * Cc * HWs);  // [4][4096][SPLITS]

    prep_k<<<dim3(2048), dim3(256), 0, stream>>>(content, content_s, style, out, Kt, Vt);
    attn_k<<<dim3(SPLITS * Bb * 32), dim3(256), 0, stream>>>(content, Kt, Vt, Opart, ml);
    combine_k<<<dim3(4096), dim3(256), 0, stream>>>(Opart, ml, out);
}